// Round 2
// baseline (2490.215 us; speedup 1.0000x reference)
//
#include <hip/hip_runtime.h>

#define N_FM 100000
#define N_TP 4096
#define N_SM 100000
#define HID 128
#define E_QOQ 1000000
#define E_BP 1000000
#define E_CP 500000
#define E_CD 500000
#define E_RB 1000000

// ---------------------------------------------------------------- pe = pe_table * period_vol
__global__ void pe_kernel(const float* __restrict__ pe_table, const float* __restrict__ pvol,
                          float* __restrict__ pe) {
    int i = blockIdx.x * blockDim.x + threadIdx.x;
    if (i < N_TP * 32) pe[i] = pe_table[i] * pvol[i >> 5];
}

// ---------------------------------------------------------------- wr_comb = qoq_Wr + cp_Wr + rb_Wr
__global__ void wr_comb_kernel(const float* __restrict__ a, const float* __restrict__ b,
                               const float* __restrict__ c, float* __restrict__ o) {
    int i = blockIdx.x * blockDim.x + threadIdx.x;
    if (i < 64 * HID) o[i] = a[i] + b[i] + c[i];
}

// ---------------------------------------------------------------- edge scatter-add (mean numerator + counts)
// one lane per (edge, feature); F consecutive lanes share an edge -> broadcast idx loads,
// coalesced gather, coalesced atomics
template <int LOGF>
__global__ void edge_scatter(const int* __restrict__ src, const int* __restrict__ dst, int nE,
                             const float* __restrict__ feat, float* __restrict__ acc,
                             float* __restrict__ cnt) {
    const int F = 1 << LOGF;
    int gid = blockIdx.x * blockDim.x + threadIdx.x;
    int e = gid >> LOGF;
    if (e >= nE) return;
    int f = gid & (F - 1);
    int s = src[e];
    int d = dst[e];
    float v = feat[(size_t)s * F + f];
    unsafeAtomicAdd(&acc[(size_t)d * F + f], v);
    if (f == 0) unsafeAtomicAdd(&cnt[d], 1.0f);
}

// ---------------------------------------------------------------- fused per-row: mean-div + linear + LN + relu + colsum
// fm rows: out = (m_qoq@Wl_q + m_cp@Wl_c + m_rb@Wl_r + x@(sum Wr) + sum bl) / 3
__global__ void fm_rows(const float* __restrict__ acc_qoq, const float* __restrict__ cnt_qoq,
                        const float* __restrict__ acc_cp, const float* __restrict__ cnt_cp,
                        const float* __restrict__ acc_rb, const float* __restrict__ cnt_rb,
                        const float* __restrict__ x_fm,
                        const float* __restrict__ Wl_q, const float* __restrict__ Wl_c,
                        const float* __restrict__ Wl_r, const float* __restrict__ wr_comb,
                        const float* __restrict__ bl_q, const float* __restrict__ bl_c,
                        const float* __restrict__ bl_r,
                        const float* __restrict__ ln_g, const float* __restrict__ ln_b,
                        float* __restrict__ colsum) {
    const int c = threadIdx.x;  // 0..127
    __shared__ float s_in[192];
    __shared__ float s_w[2], s_q[2];
    const float bias = bl_q[c] + bl_c[c] + bl_r[c];
    const float gc = ln_g[c], bc = ln_b[c];
    float colacc = 0.0f;
    for (int r = blockIdx.x; r < N_FM; r += gridDim.x) {
        if (c < 64) {
            float ic = 1.0f / fmaxf(cnt_qoq[r], 1.0f);
            s_in[c] = acc_qoq[(size_t)r * 64 + c] * ic;
            s_in[128 + c] = x_fm[(size_t)r * 64 + c];
        } else if (c < 96) {
            int k = c - 64;
            float ic = 1.0f / fmaxf(cnt_cp[r], 1.0f);
            s_in[64 + k] = acc_cp[(size_t)r * 32 + k] * ic;
        } else {
            int k = c - 96;
            float ic = 1.0f / fmaxf(cnt_rb[r], 1.0f);
            s_in[96 + k] = acc_rb[(size_t)r * 32 + k] * ic;
        }
        __syncthreads();
        float a = bias;
        for (int k = 0; k < 64; k++) a += s_in[k] * Wl_q[k * HID + c];
        for (int k = 0; k < 32; k++) a += s_in[64 + k] * Wl_c[k * HID + c];
        for (int k = 0; k < 32; k++) a += s_in[96 + k] * Wl_r[k * HID + c];
        for (int k = 0; k < 64; k++) a += s_in[128 + k] * wr_comb[k * HID + c];
        a *= (1.0f / 3.0f);
        // LayerNorm over the 128 columns (2 waves)
        float s = a, q = a * a;
#pragma unroll
        for (int off = 1; off < 64; off <<= 1) {
            s += __shfl_xor(s, off);
            q += __shfl_xor(q, off);
        }
        int wid = c >> 6;
        if ((c & 63) == 0) { s_w[wid] = s; s_q[wid] = q; }
        __syncthreads();
        float tot = s_w[0] + s_w[1], totq = s_q[0] + s_q[1];
        float mu = tot * (1.0f / 128.0f);
        float var = fmaxf(totq * (1.0f / 128.0f) - mu * mu, 0.0f);
        float y = (a - mu) * rsqrtf(var + 1e-5f) * gc + bc;
        colacc += fmaxf(y, 0.0f);
        __syncthreads();  // s_in/s_w reuse next row
    }
    unsafeAtomicAdd(&colsum[c], colacc);
}

// generic: out = (acc/cnt)@WA + bl + xB@WB   (tp: FA=64 from bp, xB=pe; sm: FA=32 from cd, xB=x_sm)
template <int FA, int FB>
__global__ void rows_generic(int nrows, const float* __restrict__ acc, const float* __restrict__ cnt,
                             const float* __restrict__ xB, const float* __restrict__ WA,
                             const float* __restrict__ WB, const float* __restrict__ bl,
                             const float* __restrict__ ln_g, const float* __restrict__ ln_b,
                             float* __restrict__ colsum) {
    const int c = threadIdx.x;  // 0..127
    __shared__ float s_in[FA + FB];
    __shared__ float s_w[2], s_q[2];
    const float bias = bl[c];
    const float gc = ln_g[c], bc = ln_b[c];
    float colacc = 0.0f;
    for (int r = blockIdx.x; r < nrows; r += gridDim.x) {
        if (c < FA) {
            float ic = 1.0f / fmaxf(cnt[r], 1.0f);
            s_in[c] = acc[(size_t)r * FA + c] * ic;
        } else if (c < FA + FB) {
            int k = c - FA;
            s_in[FA + k] = xB[(size_t)r * FB + k];
        }
        __syncthreads();
        float a = bias;
        for (int k = 0; k < FA; k++) a += s_in[k] * WA[k * HID + c];
        for (int k = 0; k < FB; k++) a += s_in[FA + k] * WB[k * HID + c];
        float s = a, q = a * a;
#pragma unroll
        for (int off = 1; off < 64; off <<= 1) {
            s += __shfl_xor(s, off);
            q += __shfl_xor(q, off);
        }
        int wid = c >> 6;
        if ((c & 63) == 0) { s_w[wid] = s; s_q[wid] = q; }
        __syncthreads();
        float tot = s_w[0] + s_w[1], totq = s_q[0] + s_q[1];
        float mu = tot * (1.0f / 128.0f);
        float var = fmaxf(totq * (1.0f / 128.0f) - mu * mu, 0.0f);
        float y = (a - mu) * rsqrtf(var + 1e-5f) * gc + bc;
        colacc += fmaxf(y, 0.0f);
        __syncthreads();
    }
    unsafeAtomicAdd(&colsum[c], colacc);
}

// ---------------------------------------------------------------- head MLP -> scalar
__global__ void head_kernel(const float* __restrict__ colsum, const float* __restrict__ gf,
                            const float* __restrict__ W1, const float* __restrict__ b1,
                            const float* __restrict__ W2, const float* __restrict__ b2,
                            float* __restrict__ out) {
    __shared__ float h[448];
    __shared__ float h1[64];
    int t = threadIdx.x;  // 512 threads
    if (t < 128) h[t] = colsum[t] * (1.0f / N_FM);
    else if (t < 256) h[t] = colsum[t] * (1.0f / N_TP);
    else if (t < 384) h[t] = colsum[t] * (1.0f / N_SM);
    else if (t < 448) h[t] = gf[t - 384];
    __syncthreads();
    if (t < 64) {
        float a = b1[t];
        for (int k = 0; k < 448; k++) a += h[k] * W1[k * 64 + t];
        h1[t] = fmaxf(a, 0.0f);
    }
    __syncthreads();
    if (t < 64) {
        float p = h1[t] * W2[t];
#pragma unroll
        for (int off = 1; off < 64; off <<= 1) p += __shfl_xor(p, off);
        if (t == 0) out[0] = p + b2[0];
    }
}

extern "C" void kernel_launch(void* const* d_in, const int* in_sizes, int n_in,
                              void* d_out, int out_size, void* d_ws, size_t ws_size,
                              hipStream_t stream) {
    const float* x_fm = (const float*)d_in[0];
    const float* x_sm = (const float*)d_in[1];
    const float* period_vol = (const float*)d_in[2];
    const float* gf = (const float*)d_in[3];
    const float* pe_table = (const float*)d_in[4];
    const int* qoq_src = (const int*)d_in[5];
    const int* qoq_dst = (const int*)d_in[6];
    const int* bp_src = (const int*)d_in[7];
    const int* bp_dst = (const int*)d_in[8];
    const int* cp_src = (const int*)d_in[9];
    const int* cp_dst = (const int*)d_in[10];
    const int* cd_src = (const int*)d_in[11];
    const int* cd_dst = (const int*)d_in[12];
    const int* rb_src = (const int*)d_in[13];
    const int* rb_dst = (const int*)d_in[14];
    const float* qoq_Wl = (const float*)d_in[15];
    const float* qoq_bl = (const float*)d_in[16];
    const float* qoq_Wr = (const float*)d_in[17];
    const float* bp_Wl = (const float*)d_in[18];
    const float* bp_bl = (const float*)d_in[19];
    const float* bp_Wr = (const float*)d_in[20];
    const float* cp_Wl = (const float*)d_in[21];
    const float* cp_bl = (const float*)d_in[22];
    const float* cp_Wr = (const float*)d_in[23];
    const float* cd_Wl = (const float*)d_in[24];
    const float* cd_bl = (const float*)d_in[25];
    const float* cd_Wr = (const float*)d_in[26];
    const float* rb_Wl = (const float*)d_in[27];
    const float* rb_bl = (const float*)d_in[28];
    const float* rb_Wr = (const float*)d_in[29];
    const float* ln_fm_g = (const float*)d_in[30];
    const float* ln_fm_b = (const float*)d_in[31];
    const float* ln_tp_g = (const float*)d_in[32];
    const float* ln_tp_b = (const float*)d_in[33];
    const float* ln_sm_g = (const float*)d_in[34];
    const float* ln_sm_b = (const float*)d_in[35];
    const float* head_W1 = (const float*)d_in[36];
    const float* head_b1 = (const float*)d_in[37];
    const float* head_W2 = (const float*)d_in[38];
    const float* head_b2 = (const float*)d_in[39];

    // workspace layout (fp32)
    float* ws = (float*)d_ws;
    size_t off = 0;
    float* acc_qoq = ws + off; off += (size_t)N_FM * 64;
    float* acc_cp  = ws + off; off += (size_t)N_FM * 32;
    float* acc_rb  = ws + off; off += (size_t)N_FM * 32;
    float* acc_bp  = ws + off; off += (size_t)N_TP * 64;
    float* acc_cd  = ws + off; off += (size_t)N_SM * 32;
    float* cnt_qoq = ws + off; off += N_FM;
    float* cnt_cp  = ws + off; off += N_FM;
    float* cnt_rb  = ws + off; off += N_FM;
    float* cnt_bp  = ws + off; off += N_TP;
    float* cnt_cd  = ws + off; off += N_SM;
    float* colsum  = ws + off; off += 384;
    size_t zero_floats = off;
    float* pe      = ws + off; off += (size_t)N_TP * 32;
    float* wr_comb = ws + off; off += 64 * HID;

    hipMemsetAsync(d_ws, 0, zero_floats * sizeof(float), stream);

    pe_kernel<<<(N_TP * 32 + 255) / 256, 256, 0, stream>>>(pe_table, period_vol, pe);
    wr_comb_kernel<<<(64 * HID + 255) / 256, 256, 0, stream>>>(qoq_Wr, cp_Wr, rb_Wr, wr_comb);

    edge_scatter<6><<<((size_t)E_QOQ * 64 + 255) / 256, 256, 0, stream>>>(
        qoq_src, qoq_dst, E_QOQ, x_fm, acc_qoq, cnt_qoq);
    edge_scatter<6><<<((size_t)E_BP * 64 + 255) / 256, 256, 0, stream>>>(
        bp_src, bp_dst, E_BP, x_fm, acc_bp, cnt_bp);
    edge_scatter<5><<<((size_t)E_CP * 32 + 255) / 256, 256, 0, stream>>>(
        cp_src, cp_dst, E_CP, pe, acc_cp, cnt_cp);
    edge_scatter<5><<<((size_t)E_CD * 32 + 255) / 256, 256, 0, stream>>>(
        cd_src, cd_dst, E_CD, pe, acc_cd, cnt_cd);
    edge_scatter<5><<<((size_t)E_RB * 32 + 255) / 256, 256, 0, stream>>>(
        rb_src, rb_dst, E_RB, pe, acc_rb, cnt_rb);

    fm_rows<<<2048, 128, 0, stream>>>(acc_qoq, cnt_qoq, acc_cp, cnt_cp, acc_rb, cnt_rb, x_fm,
                                      qoq_Wl, cp_Wl, rb_Wl, wr_comb, qoq_bl, cp_bl, rb_bl,
                                      ln_fm_g, ln_fm_b, colsum);
    rows_generic<64, 32><<<1024, 128, 0, stream>>>(N_TP, acc_bp, cnt_bp, pe, bp_Wl, bp_Wr,
                                                   bp_bl, ln_tp_g, ln_tp_b, colsum + 128);
    rows_generic<32, 32><<<2048, 128, 0, stream>>>(N_SM, acc_cd, cnt_cd, x_sm, cd_Wl, cd_Wr,
                                                   cd_bl, ln_sm_g, ln_sm_b, colsum + 256);

    head_kernel<<<1, 512, 0, stream>>>(colsum, gf, head_W1, head_b1, head_W2, head_b2,
                                       (float*)d_out);
}

// Round 3
// 1841.813 us; speedup vs baseline: 1.3520x; 1.3520x over previous
//
#include <hip/hip_runtime.h>

#define N_FM 100000
#define N_TP 4096
#define N_SM 100000
#define HID 128
#define E_QOQ 1000000
#define E_BP 1000000
#define E_CP 500000
#define E_CD 500000
#define E_RB 1000000
#define TR 32  // rows per tile; divides 100000, 4096

// ---------------------------------------------------------------- pe = pe_table * period_vol
__global__ void pe_kernel(const float* __restrict__ pe_table, const float* __restrict__ pvol,
                          float* __restrict__ pe) {
    int i = blockIdx.x * blockDim.x + threadIdx.x;
    if (i < N_TP * 32) pe[i] = pe_table[i] * pvol[i >> 5];
}

// ---------------------------------------------------------------- wr_comb = qoq_Wr + cp_Wr + rb_Wr
__global__ void wr_comb_kernel(const float* __restrict__ a, const float* __restrict__ b,
                               const float* __restrict__ c, float* __restrict__ o) {
    int i = blockIdx.x * blockDim.x + threadIdx.x;
    if (i < 64 * HID) o[i] = a[i] + b[i] + c[i];
}

// ---------------------------------------------------------------- edge scatter-add
// one lane per (edge,feature); F consecutive lanes share an edge. UNR edges per thread with
// index+gather prefetch for memory-level parallelism.
template <int LOGF, int UNR>
__global__ void edge_scatter(const int* __restrict__ src, const int* __restrict__ dst, int nE,
                             const float* __restrict__ feat, float* __restrict__ acc,
                             float* __restrict__ cnt) {
    const int F = 1 << LOGF;
    int gid = blockIdx.x * blockDim.x + threadIdx.x;
    int f = gid & (F - 1);
    int e0 = gid >> LOGF;
    int estride = (gridDim.x * blockDim.x) >> LOGF;
    int sj[UNR], dj[UNR];
#pragma unroll
    for (int j = 0; j < UNR; j++) {
        int e = e0 + j * estride;
        if (e < nE) { sj[j] = src[e]; dj[j] = dst[e]; } else { sj[j] = -1; }
    }
    float vj[UNR];
#pragma unroll
    for (int j = 0; j < UNR; j++)
        if (sj[j] >= 0) vj[j] = feat[(size_t)sj[j] * F + f];
#pragma unroll
    for (int j = 0; j < UNR; j++)
        if (sj[j] >= 0) {
            unsafeAtomicAdd(&acc[(size_t)dj[j] * F + f], vj[j]);
            if (f == 0) unsafeAtomicAdd(&cnt[dj[j]], 1.0f);
        }
}

// ---------------------------------------------------------------- LN + relu + colsum epilogue helper
__device__ __forceinline__ void ln_relu_colsum(float accv[TR], float gc, float bc,
                                               float (*s_w)[TR], float (*s_q)[TR],
                                               float& colacc, int c) {
    int wid = c >> 6;
#pragma unroll
    for (int r = 0; r < TR; r++) {
        float s = accv[r], q = accv[r] * accv[r];
#pragma unroll
        for (int off = 1; off < 64; off <<= 1) {
            s += __shfl_xor(s, off);
            q += __shfl_xor(q, off);
        }
        if ((c & 63) == 0) { s_w[wid][r] = s; s_q[wid][r] = q; }
    }
    __syncthreads();
#pragma unroll
    for (int r = 0; r < TR; r++) {
        float tot = s_w[0][r] + s_w[1][r], totq = s_q[0][r] + s_q[1][r];
        float mu = tot * (1.0f / 128.0f);
        float var = fmaxf(totq * (1.0f / 128.0f) - mu * mu, 0.0f);
        float y = (accv[r] - mu) * rsqrtf(var + 1e-5f) * gc + bc;
        colacc += fmaxf(y, 0.0f);
    }
    __syncthreads();  // LDS reuse next tile
}

// ---------------------------------------------------------------- fm rows, tiled TR rows/iter
// K layout: [qoq mean 0..63 | cp mean 64..95 | rb mean 96..127 | x_fm 128..191]
__global__ void fm_rows(const float* __restrict__ acc_qoq, const float* __restrict__ cnt_qoq,
                        const float* __restrict__ acc_cp, const float* __restrict__ cnt_cp,
                        const float* __restrict__ acc_rb, const float* __restrict__ cnt_rb,
                        const float* __restrict__ x_fm,
                        const float* __restrict__ Wl_q, const float* __restrict__ Wl_c,
                        const float* __restrict__ Wl_r, const float* __restrict__ wr_comb,
                        const float* __restrict__ bl_q, const float* __restrict__ bl_c,
                        const float* __restrict__ bl_r,
                        const float* __restrict__ ln_g, const float* __restrict__ ln_b,
                        float* __restrict__ colsum) {
    const int c = threadIdx.x;  // 0..127
    __shared__ __align__(16) float s_in[TR][192];
    __shared__ float s_ic[3][TR];
    __shared__ float s_w[2][TR], s_q[2][TR];
    const float bias = bl_q[c] + bl_c[c] + bl_r[c];
    const float gc = ln_g[c], bc = ln_b[c];
    float colacc = 0.0f;
    const int ntiles = N_FM / TR;
    for (int tile = blockIdx.x; tile < ntiles; tile += gridDim.x) {
        const size_t row0 = (size_t)tile * TR;
        if (c < TR) s_ic[0][c] = 1.0f / fmaxf(cnt_qoq[row0 + c], 1.0f);
        else if (c < 2 * TR) s_ic[1][c - TR] = 1.0f / fmaxf(cnt_cp[row0 + c - TR], 1.0f);
        else if (c < 3 * TR) s_ic[2][c - 2 * TR] = 1.0f / fmaxf(cnt_rb[row0 + c - 2 * TR], 1.0f);
        __syncthreads();
        // qoq mean (width 64 -> 16 float4/row)
        for (int i = c; i < TR * 16; i += 128) {
            int r = i >> 4;
            float4 v = ((const float4*)acc_qoq)[row0 * 16 + i];
            float ic = s_ic[0][r];
            *(float4*)&s_in[r][(i & 15) * 4] =
                make_float4(v.x * ic, v.y * ic, v.z * ic, v.w * ic);
        }
        // cp mean (width 32 -> 8 float4/row)
        for (int i = c; i < TR * 8; i += 128) {
            int r = i >> 3;
            float4 v = ((const float4*)acc_cp)[row0 * 8 + i];
            float ic = s_ic[1][r];
            *(float4*)&s_in[r][64 + (i & 7) * 4] =
                make_float4(v.x * ic, v.y * ic, v.z * ic, v.w * ic);
        }
        // rb mean
        for (int i = c; i < TR * 8; i += 128) {
            int r = i >> 3;
            float4 v = ((const float4*)acc_rb)[row0 * 8 + i];
            float ic = s_ic[2][r];
            *(float4*)&s_in[r][96 + (i & 7) * 4] =
                make_float4(v.x * ic, v.y * ic, v.z * ic, v.w * ic);
        }
        // x_fm (width 64)
        for (int i = c; i < TR * 16; i += 128) {
            int r = i >> 4;
            *(float4*)&s_in[r][128 + (i & 15) * 4] = ((const float4*)x_fm)[row0 * 16 + i];
        }
        __syncthreads();
        float accv[TR];
#pragma unroll
        for (int r = 0; r < TR; r++) accv[r] = 0.0f;
        // segment helper macro: weights loaded once per 32 rows
#define SEG(W, LEN, OFF)                                                        \
        for (int k = 0; k < LEN; k += 4) {                                      \
            float w0 = W[(k + 0) * HID + c], w1 = W[(k + 1) * HID + c];         \
            float w2 = W[(k + 2) * HID + c], w3 = W[(k + 3) * HID + c];         \
            _Pragma("unroll")                                                   \
            for (int r = 0; r < TR; r++) {                                      \
                float4 v = *(const float4*)&s_in[r][OFF + k];                    \
                accv[r] += v.x * w0 + v.y * w1 + v.z * w2 + v.w * w3;           \
            }                                                                   \
        }
        SEG(Wl_q, 64, 0)
        SEG(Wl_c, 32, 64)
        SEG(Wl_r, 32, 96)
        SEG(wr_comb, 64, 128)
#undef SEG
#pragma unroll
        for (int r = 0; r < TR; r++) accv[r] = (accv[r] + bias) * (1.0f / 3.0f);
        ln_relu_colsum(accv, gc, bc, s_w, s_q, colacc, c);
    }
    unsafeAtomicAdd(&colsum[c], colacc);
}

// ---------------------------------------------------------------- generic tiled rows
// out = (acc/cnt)@WA + xB@WB + bl ; tp: WA_=64 (bp), xB=pe ; sm: WA_=32 (cd), xB=x_sm
template <int WA_, int WB_>
__global__ void rows_tiled(int ntiles, const float* __restrict__ acc, const float* __restrict__ cnt,
                           const float* __restrict__ xB, const float* __restrict__ WA,
                           const float* __restrict__ WB, const float* __restrict__ bl,
                           const float* __restrict__ ln_g, const float* __restrict__ ln_b,
                           float* __restrict__ colsum) {
    const int c = threadIdx.x;  // 0..127
    __shared__ __align__(16) float s_in[TR][WA_ + WB_];
    __shared__ float s_ic[TR];
    __shared__ float s_w[2][TR], s_q[2][TR];
    const float bias = bl[c];
    const float gc = ln_g[c], bc = ln_b[c];
    float colacc = 0.0f;
    for (int tile = blockIdx.x; tile < ntiles; tile += gridDim.x) {
        const size_t row0 = (size_t)tile * TR;
        if (c < TR) s_ic[c] = 1.0f / fmaxf(cnt[row0 + c], 1.0f);
        __syncthreads();
        const int A4 = WA_ / 4, B4 = WB_ / 4;
        for (int i = c; i < TR * A4; i += 128) {
            int r = i / A4;
            float4 v = ((const float4*)acc)[row0 * A4 + i];
            float ic = s_ic[r];
            *(float4*)&s_in[r][(i % A4) * 4] =
                make_float4(v.x * ic, v.y * ic, v.z * ic, v.w * ic);
        }
        for (int i = c; i < TR * B4; i += 128) {
            int r = i / B4;
            *(float4*)&s_in[r][WA_ + (i % B4) * 4] = ((const float4*)xB)[row0 * B4 + i];
        }
        __syncthreads();
        float accv[TR];
#pragma unroll
        for (int r = 0; r < TR; r++) accv[r] = 0.0f;
        for (int k = 0; k < WA_; k += 4) {
            float w0 = WA[(k + 0) * HID + c], w1 = WA[(k + 1) * HID + c];
            float w2 = WA[(k + 2) * HID + c], w3 = WA[(k + 3) * HID + c];
#pragma unroll
            for (int r = 0; r < TR; r++) {
                float4 v = *(const float4*)&s_in[r][k];
                accv[r] += v.x * w0 + v.y * w1 + v.z * w2 + v.w * w3;
            }
        }
        for (int k = 0; k < WB_; k += 4) {
            float w0 = WB[(k + 0) * HID + c], w1 = WB[(k + 1) * HID + c];
            float w2 = WB[(k + 2) * HID + c], w3 = WB[(k + 3) * HID + c];
#pragma unroll
            for (int r = 0; r < TR; r++) {
                float4 v = *(const float4*)&s_in[r][WA_ + k];
                accv[r] += v.x * w0 + v.y * w1 + v.z * w2 + v.w * w3;
            }
        }
#pragma unroll
        for (int r = 0; r < TR; r++) accv[r] += bias;
        ln_relu_colsum(accv, gc, bc, s_w, s_q, colacc, c);
    }
    unsafeAtomicAdd(&colsum[c], colacc);
}

// ---------------------------------------------------------------- head MLP -> scalar
__global__ void head_kernel(const float* __restrict__ colsum, const float* __restrict__ gf,
                            const float* __restrict__ W1, const float* __restrict__ b1,
                            const float* __restrict__ W2, const float* __restrict__ b2,
                            float* __restrict__ out) {
    __shared__ float h[448];
    __shared__ float h1[64];
    int t = threadIdx.x;  // 512 threads
    if (t < 128) h[t] = colsum[t] * (1.0f / N_FM);
    else if (t < 256) h[t] = colsum[t] * (1.0f / N_TP);
    else if (t < 384) h[t] = colsum[t] * (1.0f / N_SM);
    else if (t < 448) h[t] = gf[t - 384];
    __syncthreads();
    if (t < 64) {
        float a = b1[t];
        for (int k = 0; k < 448; k++) a += h[k] * W1[k * 64 + t];
        h1[t] = fmaxf(a, 0.0f);
    }
    __syncthreads();
    if (t < 64) {
        float p = h1[t] * W2[t];
#pragma unroll
        for (int off = 1; off < 64; off <<= 1) p += __shfl_xor(p, off);
        if (t == 0) out[0] = p + b2[0];
    }
}

extern "C" void kernel_launch(void* const* d_in, const int* in_sizes, int n_in,
                              void* d_out, int out_size, void* d_ws, size_t ws_size,
                              hipStream_t stream) {
    const float* x_fm = (const float*)d_in[0];
    const float* x_sm = (const float*)d_in[1];
    const float* period_vol = (const float*)d_in[2];
    const float* gf = (const float*)d_in[3];
    const float* pe_table = (const float*)d_in[4];
    const int* qoq_src = (const int*)d_in[5];
    const int* qoq_dst = (const int*)d_in[6];
    const int* bp_src = (const int*)d_in[7];
    const int* bp_dst = (const int*)d_in[8];
    const int* cp_src = (const int*)d_in[9];
    const int* cp_dst = (const int*)d_in[10];
    const int* cd_src = (const int*)d_in[11];
    const int* cd_dst = (const int*)d_in[12];
    const int* rb_src = (const int*)d_in[13];
    const int* rb_dst = (const int*)d_in[14];
    const float* qoq_Wl = (const float*)d_in[15];
    const float* qoq_bl = (const float*)d_in[16];
    const float* qoq_Wr = (const float*)d_in[17];
    const float* bp_Wl = (const float*)d_in[18];
    const float* bp_bl = (const float*)d_in[19];
    const float* bp_Wr = (const float*)d_in[20];
    const float* cp_Wl = (const float*)d_in[21];
    const float* cp_bl = (const float*)d_in[22];
    const float* cp_Wr = (const float*)d_in[23];
    const float* cd_Wl = (const float*)d_in[24];
    const float* cd_bl = (const float*)d_in[25];
    const float* cd_Wr = (const float*)d_in[26];
    const float* rb_Wl = (const float*)d_in[27];
    const float* rb_bl = (const float*)d_in[28];
    const float* rb_Wr = (const float*)d_in[29];
    const float* ln_fm_g = (const float*)d_in[30];
    const float* ln_fm_b = (const float*)d_in[31];
    const float* ln_tp_g = (const float*)d_in[32];
    const float* ln_tp_b = (const float*)d_in[33];
    const float* ln_sm_g = (const float*)d_in[34];
    const float* ln_sm_b = (const float*)d_in[35];
    const float* head_W1 = (const float*)d_in[36];
    const float* head_b1 = (const float*)d_in[37];
    const float* head_W2 = (const float*)d_in[38];
    const float* head_b2 = (const float*)d_in[39];

    // workspace layout (fp32)
    float* ws = (float*)d_ws;
    size_t off = 0;
    float* acc_qoq = ws + off; off += (size_t)N_FM * 64;
    float* acc_cp  = ws + off; off += (size_t)N_FM * 32;
    float* acc_rb  = ws + off; off += (size_t)N_FM * 32;
    float* acc_bp  = ws + off; off += (size_t)N_TP * 64;
    float* acc_cd  = ws + off; off += (size_t)N_SM * 32;
    float* cnt_qoq = ws + off; off += N_FM;
    float* cnt_cp  = ws + off; off += N_FM;
    float* cnt_rb  = ws + off; off += N_FM;
    float* cnt_bp  = ws + off; off += N_TP;
    float* cnt_cd  = ws + off; off += N_SM;
    float* colsum  = ws + off; off += 384;
    size_t zero_floats = off;
    float* pe      = ws + off; off += (size_t)N_TP * 32;
    float* wr_comb = ws + off; off += 64 * HID;

    hipMemsetAsync(d_ws, 0, zero_floats * sizeof(float), stream);

    pe_kernel<<<(N_TP * 32 + 255) / 256, 256, 0, stream>>>(pe_table, period_vol, pe);
    wr_comb_kernel<<<(64 * HID + 255) / 256, 256, 0, stream>>>(qoq_Wr, cp_Wr, rb_Wr, wr_comb);

    // edge scatters: UNR=4 edges/thread
    {
        int blocks;
        blocks = (int)((((E_QOQ + 3) / 4) * 64ull + 255) / 256);
        edge_scatter<6, 4><<<blocks, 256, 0, stream>>>(qoq_src, qoq_dst, E_QOQ, x_fm, acc_qoq, cnt_qoq);
        blocks = (int)((((E_BP + 3) / 4) * 64ull + 255) / 256);
        edge_scatter<6, 4><<<blocks, 256, 0, stream>>>(bp_src, bp_dst, E_BP, x_fm, acc_bp, cnt_bp);
        blocks = (int)((((E_CP + 3) / 4) * 32ull + 255) / 256);
        edge_scatter<5, 4><<<blocks, 256, 0, stream>>>(cp_src, cp_dst, E_CP, pe, acc_cp, cnt_cp);
        blocks = (int)((((E_CD + 3) / 4) * 32ull + 255) / 256);
        edge_scatter<5, 4><<<blocks, 256, 0, stream>>>(cd_src, cd_dst, E_CD, pe, acc_cd, cnt_cd);
        blocks = (int)((((E_RB + 3) / 4) * 32ull + 255) / 256);
        edge_scatter<5, 4><<<blocks, 256, 0, stream>>>(rb_src, rb_dst, E_RB, pe, acc_rb, cnt_rb);
    }

    fm_rows<<<2048, 128, 0, stream>>>(acc_qoq, cnt_qoq, acc_cp, cnt_cp, acc_rb, cnt_rb, x_fm,
                                      qoq_Wl, cp_Wl, rb_Wl, wr_comb, qoq_bl, cp_bl, rb_bl,
                                      ln_fm_g, ln_fm_b, colsum);
    rows_tiled<64, 32><<<N_TP / TR, 128, 0, stream>>>(N_TP / TR, acc_bp, cnt_bp, pe, bp_Wl, bp_Wr,
                                                      bp_bl, ln_tp_g, ln_tp_b, colsum + 128);
    rows_tiled<32, 32><<<2048, 128, 0, stream>>>(N_SM / TR, acc_cd, cnt_cd, x_sm, cd_Wl, cd_Wr,
                                                 cd_bl, ln_sm_g, ln_sm_b, colsum + 256);

    head_kernel<<<1, 512, 0, stream>>>(colsum, gf, head_W1, head_b1, head_W2, head_b2,
                                       (float*)d_out);
}

// Round 4
// 1403.131 us; speedup vs baseline: 1.7748x; 1.3126x over previous
//
#include <hip/hip_runtime.h>

#define N_FM 100000
#define N_TP 4096
#define N_SM 100000
#define HID 128
#define E_QOQ 1000000
#define E_BP 1000000
#define E_CP 500000
#define E_CD 500000
#define E_RB 1000000
#define TR 32  // rows per tile; divides 100000 tiles (3125) and 4096 (128)

// ---------------------------------------------------------------- pe = pe_table * period_vol
__global__ void pe_kernel(const float* __restrict__ pe_table, const float* __restrict__ pvol,
                          float* __restrict__ pe) {
    int i = blockIdx.x * blockDim.x + threadIdx.x;
    if (i < N_TP * 32) pe[i] = pe_table[i] * pvol[i >> 5];
}

// ---------------------------------------------------------------- wr_comb = qoq_Wr + cp_Wr + rb_Wr
__global__ void wr_comb_kernel(const float* __restrict__ a, const float* __restrict__ b,
                               const float* __restrict__ c, float* __restrict__ o) {
    int i = blockIdx.x * blockDim.x + threadIdx.x;
    if (i < 64 * HID) o[i] = a[i] + b[i] + c[i];
}

// ---------------------------------------------------------------- edge scatter-add
template <int LOGF, int UNR>
__global__ void edge_scatter(const int* __restrict__ src, const int* __restrict__ dst, int nE,
                             const float* __restrict__ feat, float* __restrict__ acc,
                             float* __restrict__ cnt) {
    const int F = 1 << LOGF;
    int gid = blockIdx.x * blockDim.x + threadIdx.x;
    int f = gid & (F - 1);
    int e0 = gid >> LOGF;
    int estride = (gridDim.x * blockDim.x) >> LOGF;
    int sj[UNR], dj[UNR];
#pragma unroll
    for (int j = 0; j < UNR; j++) {
        int e = e0 + j * estride;
        if (e < nE) { sj[j] = src[e]; dj[j] = dst[e]; } else { sj[j] = -1; }
    }
    float vj[UNR];
#pragma unroll
    for (int j = 0; j < UNR; j++)
        if (sj[j] >= 0) vj[j] = feat[(size_t)sj[j] * F + f];
#pragma unroll
    for (int j = 0; j < UNR; j++)
        if (sj[j] >= 0) {
            unsafeAtomicAdd(&acc[(size_t)dj[j] * F + f], vj[j]);
            if (f == 0) unsafeAtomicAdd(&cnt[dj[j]], 1.0f);
        }
}

// ---------------------------------------------------------------- LN + relu + colsum epilogue helper
__device__ __forceinline__ void ln_relu_colsum(float accv[TR], float gc, float bc,
                                               float (*s_w)[TR], float (*s_q)[TR],
                                               float& colacc, int c) {
    int wid = c >> 6;
#pragma unroll
    for (int r = 0; r < TR; r++) {
        float s = accv[r], q = accv[r] * accv[r];
#pragma unroll
        for (int off = 1; off < 64; off <<= 1) {
            s += __shfl_xor(s, off);
            q += __shfl_xor(q, off);
        }
        if ((c & 63) == 0) { s_w[wid][r] = s; s_q[wid][r] = q; }
    }
    __syncthreads();
#pragma unroll
    for (int r = 0; r < TR; r++) {
        float tot = s_w[0][r] + s_w[1][r], totq = s_q[0][r] + s_q[1][r];
        float mu = tot * (1.0f / 128.0f);
        float var = fmaxf(totq * (1.0f / 128.0f) - mu * mu, 0.0f);
        float y = (accv[r] - mu) * rsqrtf(var + 1e-5f) * gc + bc;
        colacc += fmaxf(y, 0.0f);
    }
    __syncthreads();  // LDS reuse next tile
}

// ---------------------------------------------------------------- fm rows, tiled TR rows/iter
// __launch_bounds__(128,2): 2 waves/EU min -> up to 256 VGPR/thread; keeps accv[32] in regs
// (round-3 post-mortem: default 64-VGPR cap spilled accv -> 937 MB scratch write-back)
__global__ void __launch_bounds__(128, 2)
fm_rows(const float* __restrict__ acc_qoq, const float* __restrict__ cnt_qoq,
        const float* __restrict__ acc_cp, const float* __restrict__ cnt_cp,
        const float* __restrict__ acc_rb, const float* __restrict__ cnt_rb,
        const float* __restrict__ x_fm,
        const float* __restrict__ Wl_q, const float* __restrict__ Wl_c,
        const float* __restrict__ Wl_r, const float* __restrict__ wr_comb,
        const float* __restrict__ bl_q, const float* __restrict__ bl_c,
        const float* __restrict__ bl_r,
        const float* __restrict__ ln_g, const float* __restrict__ ln_b,
        float* __restrict__ colsum) {
    const int c = threadIdx.x;  // 0..127
    __shared__ __align__(16) float s_in[TR][192];
    __shared__ float s_ic[3][TR];
    __shared__ float s_w[2][TR], s_q[2][TR];
    const float bias = bl_q[c] + bl_c[c] + bl_r[c];
    const float gc = ln_g[c], bc = ln_b[c];
    float colacc = 0.0f;
    const int ntiles = N_FM / TR;
    for (int tile = blockIdx.x; tile < ntiles; tile += gridDim.x) {
        const size_t row0 = (size_t)tile * TR;
        if (c < TR) s_ic[0][c] = 1.0f / fmaxf(cnt_qoq[row0 + c], 1.0f);
        else if (c < 2 * TR) s_ic[1][c - TR] = 1.0f / fmaxf(cnt_cp[row0 + c - TR], 1.0f);
        else if (c < 3 * TR) s_ic[2][c - 2 * TR] = 1.0f / fmaxf(cnt_rb[row0 + c - 2 * TR], 1.0f);
        __syncthreads();
        for (int i = c; i < TR * 16; i += 128) {
            int r = i >> 4;
            float4 v = ((const float4*)acc_qoq)[row0 * 16 + i];
            float ic = s_ic[0][r];
            *(float4*)&s_in[r][(i & 15) * 4] =
                make_float4(v.x * ic, v.y * ic, v.z * ic, v.w * ic);
        }
        for (int i = c; i < TR * 8; i += 128) {
            int r = i >> 3;
            float4 v = ((const float4*)acc_cp)[row0 * 8 + i];
            float ic = s_ic[1][r];
            *(float4*)&s_in[r][64 + (i & 7) * 4] =
                make_float4(v.x * ic, v.y * ic, v.z * ic, v.w * ic);
        }
        for (int i = c; i < TR * 8; i += 128) {
            int r = i >> 3;
            float4 v = ((const float4*)acc_rb)[row0 * 8 + i];
            float ic = s_ic[2][r];
            *(float4*)&s_in[r][96 + (i & 7) * 4] =
                make_float4(v.x * ic, v.y * ic, v.z * ic, v.w * ic);
        }
        for (int i = c; i < TR * 16; i += 128) {
            int r = i >> 4;
            *(float4*)&s_in[r][128 + (i & 15) * 4] = ((const float4*)x_fm)[row0 * 16 + i];
        }
        __syncthreads();
        float accv[TR];
#pragma unroll
        for (int r = 0; r < TR; r++) accv[r] = 0.0f;
#define SEG(W, LEN, OFF)                                                        \
        for (int k = 0; k < LEN; k += 4) {                                      \
            float w0 = W[(k + 0) * HID + c], w1 = W[(k + 1) * HID + c];         \
            float w2 = W[(k + 2) * HID + c], w3 = W[(k + 3) * HID + c];         \
            _Pragma("unroll")                                                   \
            for (int r = 0; r < TR; r++) {                                      \
                float4 v = *(const float4*)&s_in[r][OFF + k];                    \
                accv[r] += v.x * w0 + v.y * w1 + v.z * w2 + v.w * w3;           \
            }                                                                   \
        }
        SEG(Wl_q, 64, 0)
        SEG(Wl_c, 32, 64)
        SEG(Wl_r, 32, 96)
        SEG(wr_comb, 64, 128)
#undef SEG
#pragma unroll
        for (int r = 0; r < TR; r++) accv[r] = (accv[r] + bias) * (1.0f / 3.0f);
        ln_relu_colsum(accv, gc, bc, s_w, s_q, colacc, c);
    }
    unsafeAtomicAdd(&colsum[c], colacc);
}

// ---------------------------------------------------------------- generic tiled rows
template <int WA_, int WB_>
__global__ void __launch_bounds__(128, 2)
rows_tiled(int ntiles, const float* __restrict__ acc, const float* __restrict__ cnt,
           const float* __restrict__ xB, const float* __restrict__ WA,
           const float* __restrict__ WB, const float* __restrict__ bl,
           const float* __restrict__ ln_g, const float* __restrict__ ln_b,
           float* __restrict__ colsum) {
    const int c = threadIdx.x;  // 0..127
    __shared__ __align__(16) float s_in[TR][WA_ + WB_];
    __shared__ float s_ic[TR];
    __shared__ float s_w[2][TR], s_q[2][TR];
    const float bias = bl[c];
    const float gc = ln_g[c], bc = ln_b[c];
    float colacc = 0.0f;
    for (int tile = blockIdx.x; tile < ntiles; tile += gridDim.x) {
        const size_t row0 = (size_t)tile * TR;
        if (c < TR) s_ic[c] = 1.0f / fmaxf(cnt[row0 + c], 1.0f);
        __syncthreads();
        const int A4 = WA_ / 4, B4 = WB_ / 4;
        for (int i = c; i < TR * A4; i += 128) {
            int r = i / A4;
            float4 v = ((const float4*)acc)[row0 * A4 + i];
            float ic = s_ic[r];
            *(float4*)&s_in[r][(i % A4) * 4] =
                make_float4(v.x * ic, v.y * ic, v.z * ic, v.w * ic);
        }
        for (int i = c; i < TR * B4; i += 128) {
            int r = i / B4;
            *(float4*)&s_in[r][WA_ + (i % B4) * 4] = ((const float4*)xB)[row0 * B4 + i];
        }
        __syncthreads();
        float accv[TR];
#pragma unroll
        for (int r = 0; r < TR; r++) accv[r] = 0.0f;
        for (int k = 0; k < WA_; k += 4) {
            float w0 = WA[(k + 0) * HID + c], w1 = WA[(k + 1) * HID + c];
            float w2 = WA[(k + 2) * HID + c], w3 = WA[(k + 3) * HID + c];
#pragma unroll
            for (int r = 0; r < TR; r++) {
                float4 v = *(const float4*)&s_in[r][k];
                accv[r] += v.x * w0 + v.y * w1 + v.z * w2 + v.w * w3;
            }
        }
        for (int k = 0; k < WB_; k += 4) {
            float w0 = WB[(k + 0) * HID + c], w1 = WB[(k + 1) * HID + c];
            float w2 = WB[(k + 2) * HID + c], w3 = WB[(k + 3) * HID + c];
#pragma unroll
            for (int r = 0; r < TR; r++) {
                float4 v = *(const float4*)&s_in[r][WA_ + k];
                accv[r] += v.x * w0 + v.y * w1 + v.z * w2 + v.w * w3;
            }
        }
#pragma unroll
        for (int r = 0; r < TR; r++) accv[r] += bias;
        ln_relu_colsum(accv, gc, bc, s_w, s_q, colacc, c);
    }
    unsafeAtomicAdd(&colsum[c], colacc);
}

// ---------------------------------------------------------------- head MLP -> scalar
__global__ void head_kernel(const float* __restrict__ colsum, const float* __restrict__ gf,
                            const float* __restrict__ W1, const float* __restrict__ b1,
                            const float* __restrict__ W2, const float* __restrict__ b2,
                            float* __restrict__ out) {
    __shared__ float h[448];
    __shared__ float h1[64];
    int t = threadIdx.x;  // 512 threads
    if (t < 128) h[t] = colsum[t] * (1.0f / N_FM);
    else if (t < 256) h[t] = colsum[t] * (1.0f / N_TP);
    else if (t < 384) h[t] = colsum[t] * (1.0f / N_SM);
    else if (t < 448) h[t] = gf[t - 384];
    __syncthreads();
    if (t < 64) {
        float a = b1[t];
        for (int k = 0; k < 448; k++) a += h[k] * W1[k * 64 + t];
        h1[t] = fmaxf(a, 0.0f);
    }
    __syncthreads();
    if (t < 64) {
        float p = h1[t] * W2[t];
#pragma unroll
        for (int off = 1; off < 64; off <<= 1) p += __shfl_xor(p, off);
        if (t == 0) out[0] = p + b2[0];
    }
}

extern "C" void kernel_launch(void* const* d_in, const int* in_sizes, int n_in,
                              void* d_out, int out_size, void* d_ws, size_t ws_size,
                              hipStream_t stream) {
    const float* x_fm = (const float*)d_in[0];
    const float* x_sm = (const float*)d_in[1];
    const float* period_vol = (const float*)d_in[2];
    const float* gf = (const float*)d_in[3];
    const float* pe_table = (const float*)d_in[4];
    const int* qoq_src = (const int*)d_in[5];
    const int* qoq_dst = (const int*)d_in[6];
    const int* bp_src = (const int*)d_in[7];
    const int* bp_dst = (const int*)d_in[8];
    const int* cp_src = (const int*)d_in[9];
    const int* cp_dst = (const int*)d_in[10];
    const int* cd_src = (const int*)d_in[11];
    const int* cd_dst = (const int*)d_in[12];
    const int* rb_src = (const int*)d_in[13];
    const int* rb_dst = (const int*)d_in[14];
    const float* qoq_Wl = (const float*)d_in[15];
    const float* qoq_bl = (const float*)d_in[16];
    const float* qoq_Wr = (const float*)d_in[17];
    const float* bp_Wl = (const float*)d_in[18];
    const float* bp_bl = (const float*)d_in[19];
    const float* bp_Wr = (const float*)d_in[20];
    const float* cp_Wl = (const float*)d_in[21];
    const float* cp_bl = (const float*)d_in[22];
    const float* cp_Wr = (const float*)d_in[23];
    const float* cd_Wl = (const float*)d_in[24];
    const float* cd_bl = (const float*)d_in[25];
    const float* cd_Wr = (const float*)d_in[26];
    const float* rb_Wl = (const float*)d_in[27];
    const float* rb_bl = (const float*)d_in[28];
    const float* rb_Wr = (const float*)d_in[29];
    const float* ln_fm_g = (const float*)d_in[30];
    const float* ln_fm_b = (const float*)d_in[31];
    const float* ln_tp_g = (const float*)d_in[32];
    const float* ln_tp_b = (const float*)d_in[33];
    const float* ln_sm_g = (const float*)d_in[34];
    const float* ln_sm_b = (const float*)d_in[35];
    const float* head_W1 = (const float*)d_in[36];
    const float* head_b1 = (const float*)d_in[37];
    const float* head_W2 = (const float*)d_in[38];
    const float* head_b2 = (const float*)d_in[39];

    // workspace layout (fp32)
    float* ws = (float*)d_ws;
    size_t off = 0;
    float* acc_qoq = ws + off; off += (size_t)N_FM * 64;
    float* acc_cp  = ws + off; off += (size_t)N_FM * 32;
    float* acc_rb  = ws + off; off += (size_t)N_FM * 32;
    float* acc_bp  = ws + off; off += (size_t)N_TP * 64;
    float* acc_cd  = ws + off; off += (size_t)N_SM * 32;
    float* cnt_qoq = ws + off; off += N_FM;
    float* cnt_cp  = ws + off; off += N_FM;
    float* cnt_rb  = ws + off; off += N_FM;
    float* cnt_bp  = ws + off; off += N_TP;
    float* cnt_cd  = ws + off; off += N_SM;
    float* colsum  = ws + off; off += 384;
    size_t zero_floats = off;
    float* pe      = ws + off; off += (size_t)N_TP * 32;
    float* wr_comb = ws + off; off += 64 * HID;

    hipMemsetAsync(d_ws, 0, zero_floats * sizeof(float), stream);

    pe_kernel<<<(N_TP * 32 + 255) / 256, 256, 0, stream>>>(pe_table, period_vol, pe);
    wr_comb_kernel<<<(64 * HID + 255) / 256, 256, 0, stream>>>(qoq_Wr, cp_Wr, rb_Wr, wr_comb);

    {
        int blocks;
        blocks = (int)((((E_QOQ + 3) / 4) * 64ull + 255) / 256);
        edge_scatter<6, 4><<<blocks, 256, 0, stream>>>(qoq_src, qoq_dst, E_QOQ, x_fm, acc_qoq, cnt_qoq);
        blocks = (int)((((E_BP + 3) / 4) * 64ull + 255) / 256);
        edge_scatter<6, 4><<<blocks, 256, 0, stream>>>(bp_src, bp_dst, E_BP, x_fm, acc_bp, cnt_bp);
        blocks = (int)((((E_CP + 3) / 4) * 32ull + 255) / 256);
        edge_scatter<5, 4><<<blocks, 256, 0, stream>>>(cp_src, cp_dst, E_CP, pe, acc_cp, cnt_cp);
        blocks = (int)((((E_CD + 3) / 4) * 32ull + 255) / 256);
        edge_scatter<5, 4><<<blocks, 256, 0, stream>>>(cd_src, cd_dst, E_CD, pe, acc_cd, cnt_cd);
        blocks = (int)((((E_RB + 3) / 4) * 32ull + 255) / 256);
        edge_scatter<5, 4><<<blocks, 256, 0, stream>>>(rb_src, rb_dst, E_RB, pe, acc_rb, cnt_rb);
    }

    fm_rows<<<2048, 128, 0, stream>>>(acc_qoq, cnt_qoq, acc_cp, cnt_cp, acc_rb, cnt_rb, x_fm,
                                      qoq_Wl, cp_Wl, rb_Wl, wr_comb, qoq_bl, cp_bl, rb_bl,
                                      ln_fm_g, ln_fm_b, colsum);
    rows_tiled<64, 32><<<N_TP / TR, 128, 0, stream>>>(N_TP / TR, acc_bp, cnt_bp, pe, bp_Wl, bp_Wr,
                                                      bp_bl, ln_tp_g, ln_tp_b, colsum + 128);
    rows_tiled<32, 32><<<2048, 128, 0, stream>>>(N_SM / TR, acc_cd, cnt_cd, x_sm, cd_Wl, cd_Wr,
                                                 cd_bl, ln_sm_g, ln_sm_b, colsum + 256);

    head_kernel<<<1, 512, 0, stream>>>(colsum, gf, head_W1, head_b1, head_W2, head_b2,
                                       (float*)d_out);
}

// Round 5
// 1112.107 us; speedup vs baseline: 2.2392x; 1.2617x over previous
//
#include <hip/hip_runtime.h>
#include <hip/hip_bf16.h>

#define N_FM 100000
#define N_TP 4096
#define N_SM 100000
#define HID 128
#define E_QOQ 1000000
#define E_BP 1000000
#define E_CP 500000
#define E_CD 500000
#define E_RB 1000000
#define TR 32  // rows per tile

// bf16-pair helpers: packed uint = (feat2k in low16, feat2k+1 in high16)
__device__ __forceinline__ float bflo(unsigned u) { return __uint_as_float(u << 16); }
__device__ __forceinline__ float bfhi(unsigned u) { return __uint_as_float(u & 0xffff0000u); }

__device__ __forceinline__ void atomic_pk_add_bf16(unsigned* p, unsigned v) {
    asm volatile("global_atomic_pk_add_bf16 %0, %1, off" : : "v"(p), "v"(v) : "memory");
}

// ---------------------------------------------------------------- pe = pe_table * period_vol (fp32 + packed bf16)
__global__ void pe_pack_kernel(const float* __restrict__ pe_table, const float* __restrict__ pvol,
                               float* __restrict__ pe, unsigned* __restrict__ pe_bf) {
    int i = blockIdx.x * blockDim.x + threadIdx.x;  // pair index
    if (i < N_TP * 16) {
        float2 t = ((const float2*)pe_table)[i];
        float v = pvol[i >> 4];
        float2 p = make_float2(t.x * v, t.y * v);
        ((float2*)pe)[i] = p;
        __hip_bfloat162 b = __float22bfloat162_rn(p);
        pe_bf[i] = *(unsigned*)&b;
    }
}

// ---------------------------------------------------------------- x_fm -> packed bf16
__global__ void pack_x_kernel(const float* __restrict__ x, unsigned* __restrict__ xb, int npairs) {
    int i = blockIdx.x * blockDim.x + threadIdx.x;
    if (i < npairs) {
        float2 t = ((const float2*)x)[i];
        __hip_bfloat162 b = __float22bfloat162_rn(t);
        xb[i] = *(unsigned*)&b;
    }
}

// ---------------------------------------------------------------- wr_comb = qoq_Wr + cp_Wr + rb_Wr
__global__ void wr_comb_kernel(const float* __restrict__ a, const float* __restrict__ b,
                               const float* __restrict__ c, float* __restrict__ o) {
    int i = blockIdx.x * blockDim.x + threadIdx.x;
    if (i < 64 * HID) o[i] = a[i] + b[i] + c[i];
}

// ---------------------------------------------------------------- edge scatter-add, packed bf16
// L = lanes per edge; each lane handles one packed pair (2 feats, 4B) -> pk_add_bf16 atomic.
template <int LOGL, int UNR>
__global__ void edge_scatter_bf(const int* __restrict__ src, const int* __restrict__ dst, int nE,
                                const unsigned* __restrict__ feat, unsigned* __restrict__ acc,
                                float* __restrict__ cnt) {
    const int L = 1 << LOGL;
    int gid = blockIdx.x * blockDim.x + threadIdx.x;
    int f = gid & (L - 1);
    int e0 = gid >> LOGL;
    int estride = ((int)(gridDim.x * blockDim.x)) >> LOGL;
    int sj[UNR], dj[UNR];
#pragma unroll
    for (int j = 0; j < UNR; j++) {
        int e = e0 + j * estride;
        if (e < nE) { sj[j] = src[e]; dj[j] = dst[e]; } else { sj[j] = -1; }
    }
    unsigned vj[UNR];
#pragma unroll
    for (int j = 0; j < UNR; j++)
        if (sj[j] >= 0) vj[j] = feat[(size_t)sj[j] * L + f];
#pragma unroll
    for (int j = 0; j < UNR; j++)
        if (sj[j] >= 0) {
            atomic_pk_add_bf16(&acc[(size_t)dj[j] * L + f], vj[j]);
            if (f == 0) unsafeAtomicAdd(&cnt[dj[j]], 1.0f);
        }
}

// ---------------------------------------------------------------- LN + relu + colsum epilogue
__device__ __forceinline__ void ln_relu_colsum(float accv[TR], float gc, float bc,
                                               float (*s_w)[TR], float (*s_q)[TR],
                                               float& colacc, int c) {
    int wid = c >> 6;
#pragma unroll
    for (int r = 0; r < TR; r++) {
        float s = accv[r], q = accv[r] * accv[r];
#pragma unroll
        for (int off = 1; off < 64; off <<= 1) {
            s += __shfl_xor(s, off);
            q += __shfl_xor(q, off);
        }
        if ((c & 63) == 0) { s_w[wid][r] = s; s_q[wid][r] = q; }
    }
    __syncthreads();
#pragma unroll
    for (int r = 0; r < TR; r++) {
        float tot = s_w[0][r] + s_w[1][r], totq = s_q[0][r] + s_q[1][r];
        float mu = tot * (1.0f / 128.0f);
        float var = fmaxf(totq * (1.0f / 128.0f) - mu * mu, 0.0f);
        float y = (accv[r] - mu) * rsqrtf(var + 1e-5f) * gc + bc;
        colacc += fmaxf(y, 0.0f);
    }
    __syncthreads();
}

// unpack uint4 (8 bf16 feats) * ic -> 8 floats at dst
__device__ __forceinline__ void unpack8(float* o, uint4 v, float ic) {
    float4 a = make_float4(bflo(v.x) * ic, bfhi(v.x) * ic, bflo(v.y) * ic, bfhi(v.y) * ic);
    float4 b = make_float4(bflo(v.z) * ic, bfhi(v.z) * ic, bflo(v.w) * ic, bfhi(v.w) * ic);
    *(float4*)o = a;
    *(float4*)(o + 4) = b;
}

// ---------------------------------------------------------------- fm rows, tiled
// K layout: [qoq mean 0..63 | cp mean 64..95 | rb mean 96..127 | x_fm 128..191]
__global__ void __launch_bounds__(128, 2)
fm_rows(const unsigned* __restrict__ acc_qoq, const float* __restrict__ cnt_qoq,
        const unsigned* __restrict__ acc_cp, const float* __restrict__ cnt_cp,
        const unsigned* __restrict__ acc_rb, const float* __restrict__ cnt_rb,
        const float* __restrict__ x_fm,
        const float* __restrict__ Wl_q, const float* __restrict__ Wl_c,
        const float* __restrict__ Wl_r, const float* __restrict__ wr_comb,
        const float* __restrict__ bl_q, const float* __restrict__ bl_c,
        const float* __restrict__ bl_r,
        const float* __restrict__ ln_g, const float* __restrict__ ln_b,
        float* __restrict__ colsum) {
    const int c = threadIdx.x;  // 0..127
    __shared__ __align__(16) float s_in[TR][192];
    __shared__ float s_ic[3][TR];
    __shared__ float s_w[2][TR], s_q[2][TR];
    const float bias = bl_q[c] + bl_c[c] + bl_r[c];
    const float gc = ln_g[c], bc = ln_b[c];
    float colacc = 0.0f;
    const int ntiles = N_FM / TR;
    for (int tile = blockIdx.x; tile < ntiles; tile += gridDim.x) {
        const size_t row0 = (size_t)tile * TR;
        if (c < TR) s_ic[0][c] = 1.0f / fmaxf(cnt_qoq[row0 + c], 1.0f);
        else if (c < 2 * TR) s_ic[1][c - TR] = 1.0f / fmaxf(cnt_cp[row0 + c - TR], 1.0f);
        else if (c < 3 * TR) s_ic[2][c - 2 * TR] = 1.0f / fmaxf(cnt_rb[row0 + c - 2 * TR], 1.0f);
        __syncthreads();
        // qoq mean: 64 feats = 8 uint4/row
        for (int i = c; i < TR * 8; i += 128) {
            int r = i >> 3, q = i & 7;
            uint4 v = ((const uint4*)acc_qoq)[row0 * 8 + i];
            unpack8(&s_in[r][q * 8], v, s_ic[0][r]);
        }
        // cp mean: 32 feats = 4 uint4/row
        for (int i = c; i < TR * 4; i += 128) {
            int r = i >> 2, q = i & 3;
            uint4 v = ((const uint4*)acc_cp)[row0 * 4 + i];
            unpack8(&s_in[r][64 + q * 8], v, s_ic[1][r]);
        }
        // rb mean
        for (int i = c; i < TR * 4; i += 128) {
            int r = i >> 2, q = i & 3;
            uint4 v = ((const uint4*)acc_rb)[row0 * 4 + i];
            unpack8(&s_in[r][96 + q * 8], v, s_ic[2][r]);
        }
        // x_fm fp32: 16 float4/row
        for (int i = c; i < TR * 16; i += 128) {
            int r = i >> 4;
            *(float4*)&s_in[r][128 + (i & 15) * 4] = ((const float4*)x_fm)[row0 * 16 + i];
        }
        __syncthreads();
        float accv[TR];
#pragma unroll
        for (int r = 0; r < TR; r++) accv[r] = 0.0f;
#define SEG(W, LEN, OFF)                                                        \
        for (int k = 0; k < LEN; k += 4) {                                      \
            float w0 = W[(k + 0) * HID + c], w1 = W[(k + 1) * HID + c];         \
            float w2 = W[(k + 2) * HID + c], w3 = W[(k + 3) * HID + c];         \
            _Pragma("unroll")                                                   \
            for (int r = 0; r < TR; r++) {                                      \
                float4 v = *(const float4*)&s_in[r][OFF + k];                    \
                accv[r] += v.x * w0 + v.y * w1 + v.z * w2 + v.w * w3;           \
            }                                                                   \
        }
        SEG(Wl_q, 64, 0)
        SEG(Wl_c, 32, 64)
        SEG(Wl_r, 32, 96)
        SEG(wr_comb, 64, 128)
#undef SEG
#pragma unroll
        for (int r = 0; r < TR; r++) accv[r] = (accv[r] + bias) * (1.0f / 3.0f);
        ln_relu_colsum(accv, gc, bc, s_w, s_q, colacc, c);
    }
    unsafeAtomicAdd(&colsum[c], colacc);
}

// ---------------------------------------------------------------- generic tiled rows (A = bf16 acc, B = fp32)
template <int WA_, int WB_>
__global__ void __launch_bounds__(128, 2)
rows_tiled(int ntiles, const unsigned* __restrict__ acc, const float* __restrict__ cnt,
           const float* __restrict__ xB, const float* __restrict__ WA,
           const float* __restrict__ WB, const float* __restrict__ bl,
           const float* __restrict__ ln_g, const float* __restrict__ ln_b,
           float* __restrict__ colsum) {
    const int c = threadIdx.x;  // 0..127
    __shared__ __align__(16) float s_in[TR][WA_ + WB_];
    __shared__ float s_ic[TR];
    __shared__ float s_w[2][TR], s_q[2][TR];
    const float bias = bl[c];
    const float gc = ln_g[c], bc = ln_b[c];
    float colacc = 0.0f;
    const int A8 = WA_ / 8, B4 = WB_ / 4;
    for (int tile = blockIdx.x; tile < ntiles; tile += gridDim.x) {
        const size_t row0 = (size_t)tile * TR;
        if (c < TR) s_ic[c] = 1.0f / fmaxf(cnt[row0 + c], 1.0f);
        __syncthreads();
        for (int i = c; i < TR * A8; i += 128) {
            int r = i / A8, q = i % A8;
            uint4 v = ((const uint4*)acc)[row0 * A8 + i];
            unpack8(&s_in[r][q * 8], v, s_ic[r]);
        }
        for (int i = c; i < TR * B4; i += 128) {
            int r = i / B4;
            *(float4*)&s_in[r][WA_ + (i % B4) * 4] = ((const float4*)xB)[row0 * B4 + i];
        }
        __syncthreads();
        float accv[TR];
#pragma unroll
        for (int r = 0; r < TR; r++) accv[r] = 0.0f;
        for (int k = 0; k < WA_; k += 4) {
            float w0 = WA[(k + 0) * HID + c], w1 = WA[(k + 1) * HID + c];
            float w2 = WA[(k + 2) * HID + c], w3 = WA[(k + 3) * HID + c];
#pragma unroll
            for (int r = 0; r < TR; r++) {
                float4 v = *(const float4*)&s_in[r][k];
                accv[r] += v.x * w0 + v.y * w1 + v.z * w2 + v.w * w3;
            }
        }
        for (int k = 0; k < WB_; k += 4) {
            float w0 = WB[(k + 0) * HID + c], w1 = WB[(k + 1) * HID + c];
            float w2 = WB[(k + 2) * HID + c], w3 = WB[(k + 3) * HID + c];
#pragma unroll
            for (int r = 0; r < TR; r++) {
                float4 v = *(const float4*)&s_in[r][WA_ + k];
                accv[r] += v.x * w0 + v.y * w1 + v.z * w2 + v.w * w3;
            }
        }
#pragma unroll
        for (int r = 0; r < TR; r++) accv[r] += bias;
        ln_relu_colsum(accv, gc, bc, s_w, s_q, colacc, c);
    }
    unsafeAtomicAdd(&colsum[c], colacc);
}

// ---------------------------------------------------------------- head MLP -> scalar
__global__ void head_kernel(const float* __restrict__ colsum, const float* __restrict__ gf,
                            const float* __restrict__ W1, const float* __restrict__ b1,
                            const float* __restrict__ W2, const float* __restrict__ b2,
                            float* __restrict__ out) {
    __shared__ float h[448];
    __shared__ float h1[64];
    int t = threadIdx.x;  // 512 threads
    if (t < 128) h[t] = colsum[t] * (1.0f / N_FM);
    else if (t < 256) h[t] = colsum[t] * (1.0f / N_TP);
    else if (t < 384) h[t] = colsum[t] * (1.0f / N_SM);
    else if (t < 448) h[t] = gf[t - 384];
    __syncthreads();
    if (t < 64) {
        float a = b1[t];
        for (int k = 0; k < 448; k++) a += h[k] * W1[k * 64 + t];
        h1[t] = fmaxf(a, 0.0f);
    }
    __syncthreads();
    if (t < 64) {
        float p = h1[t] * W2[t];
#pragma unroll
        for (int off = 1; off < 64; off <<= 1) p += __shfl_xor(p, off);
        if (t == 0) out[0] = p + b2[0];
    }
}

extern "C" void kernel_launch(void* const* d_in, const int* in_sizes, int n_in,
                              void* d_out, int out_size, void* d_ws, size_t ws_size,
                              hipStream_t stream) {
    const float* x_fm = (const float*)d_in[0];
    const float* x_sm = (const float*)d_in[1];
    const float* period_vol = (const float*)d_in[2];
    const float* gf = (const float*)d_in[3];
    const float* pe_table = (const float*)d_in[4];
    const int* qoq_src = (const int*)d_in[5];
    const int* qoq_dst = (const int*)d_in[6];
    const int* bp_src = (const int*)d_in[7];
    const int* bp_dst = (const int*)d_in[8];
    const int* cp_src = (const int*)d_in[9];
    const int* cp_dst = (const int*)d_in[10];
    const int* cd_src = (const int*)d_in[11];
    const int* cd_dst = (const int*)d_in[12];
    const int* rb_src = (const int*)d_in[13];
    const int* rb_dst = (const int*)d_in[14];
    const float* qoq_Wl = (const float*)d_in[15];
    const float* qoq_bl = (const float*)d_in[16];
    const float* qoq_Wr = (const float*)d_in[17];
    const float* bp_Wl = (const float*)d_in[18];
    const float* bp_bl = (const float*)d_in[19];
    const float* bp_Wr = (const float*)d_in[20];
    const float* cp_Wl = (const float*)d_in[21];
    const float* cp_bl = (const float*)d_in[22];
    const float* cp_Wr = (const float*)d_in[23];
    const float* cd_Wl = (const float*)d_in[24];
    const float* cd_bl = (const float*)d_in[25];
    const float* cd_Wr = (const float*)d_in[26];
    const float* rb_Wl = (const float*)d_in[27];
    const float* rb_bl = (const float*)d_in[28];
    const float* rb_Wr = (const float*)d_in[29];
    const float* ln_fm_g = (const float*)d_in[30];
    const float* ln_fm_b = (const float*)d_in[31];
    const float* ln_tp_g = (const float*)d_in[32];
    const float* ln_tp_b = (const float*)d_in[33];
    const float* ln_sm_g = (const float*)d_in[34];
    const float* ln_sm_b = (const float*)d_in[35];
    const float* head_W1 = (const float*)d_in[36];
    const float* head_b1 = (const float*)d_in[37];
    const float* head_W2 = (const float*)d_in[38];
    const float* head_b2 = (const float*)d_in[39];

    // workspace layout: bf16 accumulators (packed pairs as uint) first, then fp32
    unsigned* wsu = (unsigned*)d_ws;
    size_t off = 0;
    unsigned* acc_qoq = wsu + off; off += (size_t)N_FM * 32;  // 64 feats packed
    unsigned* acc_cp  = wsu + off; off += (size_t)N_FM * 16;  // 32 feats packed
    unsigned* acc_rb  = wsu + off; off += (size_t)N_FM * 16;
    unsigned* acc_bp  = wsu + off; off += (size_t)N_TP * 32;
    unsigned* acc_cd  = wsu + off; off += (size_t)N_SM * 16;
    float* cnt_qoq = (float*)(wsu + off); off += N_FM;
    float* cnt_cp  = (float*)(wsu + off); off += N_FM;
    float* cnt_rb  = (float*)(wsu + off); off += N_FM;
    float* cnt_bp  = (float*)(wsu + off); off += N_TP;
    float* cnt_cd  = (float*)(wsu + off); off += N_SM;
    float* colsum  = (float*)(wsu + off); off += 384;
    size_t zero_words = off;
    float* pe       = (float*)(wsu + off); off += (size_t)N_TP * 32;
    unsigned* pe_bf  = wsu + off; off += (size_t)N_TP * 16;
    unsigned* x_fm_bf = wsu + off; off += (size_t)N_FM * 32;
    float* wr_comb  = (float*)(wsu + off); off += 64 * HID;

    hipMemsetAsync(d_ws, 0, zero_words * 4, stream);

    pe_pack_kernel<<<(N_TP * 16 + 255) / 256, 256, 0, stream>>>(pe_table, period_vol, pe, pe_bf);
    pack_x_kernel<<<(N_FM * 32 + 255) / 256, 256, 0, stream>>>(x_fm, x_fm_bf, N_FM * 32);
    wr_comb_kernel<<<(64 * HID + 255) / 256, 256, 0, stream>>>(qoq_Wr, cp_Wr, rb_Wr, wr_comb);

    // edge scatters: UNR=4 edges/thread, packed-bf16 atomics (2 feats / 4B per op)
    {
        int blocks;
        blocks = (int)((((E_QOQ + 3) / 4) * 32ull + 255) / 256);
        edge_scatter_bf<5, 4><<<blocks, 256, 0, stream>>>(qoq_src, qoq_dst, E_QOQ, x_fm_bf, acc_qoq, cnt_qoq);
        blocks = (int)((((E_BP + 3) / 4) * 32ull + 255) / 256);
        edge_scatter_bf<5, 4><<<blocks, 256, 0, stream>>>(bp_src, bp_dst, E_BP, x_fm_bf, acc_bp, cnt_bp);
        blocks = (int)((((E_CP + 3) / 4) * 16ull + 255) / 256);
        edge_scatter_bf<4, 4><<<blocks, 256, 0, stream>>>(cp_src, cp_dst, E_CP, pe_bf, acc_cp, cnt_cp);
        blocks = (int)((((E_CD + 3) / 4) * 16ull + 255) / 256);
        edge_scatter_bf<4, 4><<<blocks, 256, 0, stream>>>(cd_src, cd_dst, E_CD, pe_bf, acc_cd, cnt_cd);
        blocks = (int)((((E_RB + 3) / 4) * 16ull + 255) / 256);
        edge_scatter_bf<4, 4><<<blocks, 256, 0, stream>>>(rb_src, rb_dst, E_RB, pe_bf, acc_rb, cnt_rb);
    }

    fm_rows<<<2048, 128, 0, stream>>>(acc_qoq, cnt_qoq, acc_cp, cnt_cp, acc_rb, cnt_rb, x_fm,
                                      qoq_Wl, cp_Wl, rb_Wl, wr_comb, qoq_bl, cp_bl, rb_bl,
                                      ln_fm_g, ln_fm_b, colsum);
    rows_tiled<64, 32><<<N_TP / TR, 128, 0, stream>>>(N_TP / TR, acc_bp, cnt_bp, pe, bp_Wl, bp_Wr,
                                                      bp_bl, ln_tp_g, ln_tp_b, colsum + 128);
    rows_tiled<32, 32><<<2048, 128, 0, stream>>>(N_SM / TR, acc_cd, cnt_cd, x_sm, cd_Wl, cd_Wr,
                                                 cd_bl, ln_sm_g, ln_sm_b, colsum + 256);

    head_kernel<<<1, 512, 0, stream>>>(colsum, gf, head_W1, head_b1, head_W2, head_b2,
                                       (float*)d_out);
}

// Round 6
// 1057.283 us; speedup vs baseline: 2.3553x; 1.0519x over previous
//
#include <hip/hip_runtime.h>
#include <hip/hip_fp16.h>

#define N_FM 100000
#define N_TP 4096
#define N_SM 100000
#define HID 128
#define E_QOQ 1000000
#define E_BP 1000000
#define E_CP 500000
#define E_CD 500000
#define E_RB 1000000
#define TR 32  // rows per tile

typedef _Float16 h2 __attribute__((ext_vector_type(2)));

#if defined(__has_builtin)
#if __has_builtin(__builtin_amdgcn_fdot2)
#define HAVE_FDOT2 1
#endif
#endif

union U32H2 { unsigned u; h2 h; };

__device__ __forceinline__ unsigned pk2(float a, float b) {
    U32H2 x; x.h = h2{(_Float16)a, (_Float16)b}; return x.u;
}
__device__ __forceinline__ unsigned h2mul(unsigned a, unsigned b) {
    U32H2 x, y, r; x.u = a; y.u = b; r.h = x.h * y.h; return r.u;
}
// acc += dot(a_pair, b_pair), fp32 accumulate
__device__ __forceinline__ float dot2(float acc, unsigned a, unsigned b) {
    U32H2 x, y; x.u = a; y.u = b;
#ifdef HAVE_FDOT2
    return __builtin_amdgcn_fdot2(x.h, y.h, acc, false);
#else
    return acc + (float)x.h[0] * (float)y.h[0] + (float)x.h[1] * (float)y.h[1];
#endif
}

__device__ __forceinline__ void atomic_pk_add_f16(unsigned* p, unsigned v) {
    asm volatile("global_atomic_pk_add_f16 %0, %1, off" : : "v"(p), "v"(v) : "memory");
}

// ---------------------------------------------------------------- pe (f16 pairs) = pe_table * period_vol
__global__ void pe_pack_kernel(const float* __restrict__ pe_table, const float* __restrict__ pvol,
                               unsigned* __restrict__ pe_f) {
    int i = blockIdx.x * blockDim.x + threadIdx.x;  // pair index
    if (i < N_TP * 16) {
        float2 t = ((const float2*)pe_table)[i];
        float v = pvol[i >> 4];
        pe_f[i] = pk2(t.x * v, t.y * v);
    }
}

// ---------------------------------------------------------------- fp32 -> f16 pairs
__global__ void pack_x_kernel(const float* __restrict__ x, unsigned* __restrict__ xp, int npairs) {
    int i = blockIdx.x * blockDim.x + threadIdx.x;
    if (i < npairs) {
        float2 t = ((const float2*)x)[i];
        xp[i] = pk2(t.x, t.y);
    }
}

// ---------------------------------------------------------------- wr_comb = qoq_Wr + cp_Wr + rb_Wr (fp32)
__global__ void wr_comb_kernel(const float* __restrict__ a, const float* __restrict__ b,
                               const float* __restrict__ c, float* __restrict__ o) {
    int i = blockIdx.x * blockDim.x + threadIdx.x;
    if (i < 64 * HID) o[i] = a[i] + b[i] + c[i];
}

// ---------------------------------------------------------------- weight pack: W[K][128] fp32 -> pairs [K/2][128]
__global__ void pack_w_kernel(const float* __restrict__ W, unsigned* __restrict__ dst, int K) {
    int i = blockIdx.x * blockDim.x + threadIdx.x;
    int n = (K / 2) * HID;
    if (i < n) {
        int r = i >> 7, c = i & 127;
        dst[i] = pk2(W[(2 * r) * HID + c], W[(2 * r + 1) * HID + c]);
    }
}

// ---------------------------------------------------------------- edge scatter-add, packed f16
// L lanes per edge, one packed pair (2 feats / 4B) per lane
template <int LOGL, int UNR>
__global__ void edge_scatter_f16(const int* __restrict__ src, const int* __restrict__ dst, int nE,
                                 const unsigned* __restrict__ feat, unsigned* __restrict__ acc,
                                 float* __restrict__ cnt) {
    const int L = 1 << LOGL;
    int gid = blockIdx.x * blockDim.x + threadIdx.x;
    int f = gid & (L - 1);
    int e0 = gid >> LOGL;
    int estride = ((int)(gridDim.x * blockDim.x)) >> LOGL;
    int sj[UNR], dj[UNR];
#pragma unroll
    for (int j = 0; j < UNR; j++) {
        int e = e0 + j * estride;
        if (e < nE) { sj[j] = src[e]; dj[j] = dst[e]; } else { sj[j] = -1; }
    }
    unsigned vj[UNR];
#pragma unroll
    for (int j = 0; j < UNR; j++)
        if (sj[j] >= 0) vj[j] = feat[(size_t)sj[j] * L + f];
#pragma unroll
    for (int j = 0; j < UNR; j++)
        if (sj[j] >= 0) {
            atomic_pk_add_f16(&acc[(size_t)dj[j] * L + f], vj[j]);
            if (f == 0) unsafeAtomicAdd(&cnt[dj[j]], 1.0f);
        }
}

// ---------------------------------------------------------------- LN + relu + colsum epilogue
__device__ __forceinline__ void ln_relu_colsum(float accv[TR], float gc, float bc,
                                               float (*s_w)[TR], float (*s_q)[TR],
                                               float& colacc, int c) {
    int wid = c >> 6;
#pragma unroll
    for (int r = 0; r < TR; r++) {
        float s = accv[r], q = accv[r] * accv[r];
#pragma unroll
        for (int off = 1; off < 64; off <<= 1) {
            s += __shfl_xor(s, off);
            q += __shfl_xor(q, off);
        }
        if ((c & 63) == 0) { s_w[wid][r] = s; s_q[wid][r] = q; }
    }
    __syncthreads();
#pragma unroll
    for (int r = 0; r < TR; r++) {
        float tot = s_w[0][r] + s_w[1][r], totq = s_q[0][r] + s_q[1][r];
        float mu = tot * (1.0f / 128.0f);
        float var = fmaxf(totq * (1.0f / 128.0f) - mu * mu, 0.0f);
        float y = (accv[r] - mu) * rsqrtf(var + 1e-5f) * gc + bc;
        colacc += fmaxf(y, 0.0f);
    }
    __syncthreads();
}

__device__ __forceinline__ uint4 scale4(uint4 v, unsigned m) {
    v.x = h2mul(v.x, m); v.y = h2mul(v.y, m); v.z = h2mul(v.z, m); v.w = h2mul(v.w, m);
    return v;
}

// ---------------------------------------------------------------- fm rows (f16 packed, fdot2)
// s_in pair layout: [0..31]=qoq mean | [32..47]=cp mean | [48..63]=rb mean | [64..95]=x_fm
__global__ void __launch_bounds__(128, 3)
fm_rows_f16(const unsigned* __restrict__ acc_qoq, const float* __restrict__ cnt_qoq,
            const unsigned* __restrict__ acc_cp, const float* __restrict__ cnt_cp,
            const unsigned* __restrict__ acc_rb, const float* __restrict__ cnt_rb,
            const unsigned* __restrict__ x_fm_f, const unsigned* __restrict__ wf,
            const float* __restrict__ bl_q, const float* __restrict__ bl_c,
            const float* __restrict__ bl_r,
            const float* __restrict__ ln_g, const float* __restrict__ ln_b,
            float* __restrict__ colsum) {
    const int c = threadIdx.x;  // 0..127
    __shared__ __align__(16) unsigned s_in[TR][96];
    __shared__ unsigned s_ic2[3][TR];
    __shared__ float s_w[2][TR], s_q[2][TR];
    const float bias = bl_q[c] + bl_c[c] + bl_r[c];
    const float gc = ln_g[c], bc = ln_b[c];
    float colacc = 0.0f;
    const int ntiles = N_FM / TR;
    for (int tile = blockIdx.x; tile < ntiles; tile += gridDim.x) {
        const size_t row0 = (size_t)tile * TR;
        if (c < TR) {
            float ic = 1.0f / fmaxf(cnt_qoq[row0 + c], 1.0f); s_ic2[0][c] = pk2(ic, ic);
        } else if (c < 2 * TR) {
            float ic = 1.0f / fmaxf(cnt_cp[row0 + c - TR], 1.0f); s_ic2[1][c - TR] = pk2(ic, ic);
        } else if (c < 3 * TR) {
            float ic = 1.0f / fmaxf(cnt_rb[row0 + c - 2 * TR], 1.0f); s_ic2[2][c - 2 * TR] = pk2(ic, ic);
        }
        __syncthreads();
        // qoq: 8 uint4/row
        for (int i = c; i < TR * 8; i += 128) {
            int r = i >> 3;
            uint4 v = ((const uint4*)acc_qoq)[row0 * 8 + i];
            *(uint4*)&s_in[r][(i & 7) * 4] = scale4(v, s_ic2[0][r]);
        }
        // cp: 4 uint4/row
        for (int i = c; i < TR * 4; i += 128) {
            int r = i >> 2;
            uint4 v = ((const uint4*)acc_cp)[row0 * 4 + i];
            *(uint4*)&s_in[r][32 + (i & 3) * 4] = scale4(v, s_ic2[1][r]);
        }
        // rb: 4 uint4/row
        for (int i = c; i < TR * 4; i += 128) {
            int r = i >> 2;
            uint4 v = ((const uint4*)acc_rb)[row0 * 4 + i];
            *(uint4*)&s_in[r][48 + (i & 3) * 4] = scale4(v, s_ic2[2][r]);
        }
        // x_fm: 8 uint4/row, no scale
        for (int i = c; i < TR * 8; i += 128) {
            int r = i >> 3;
            *(uint4*)&s_in[r][64 + (i & 7) * 4] = ((const uint4*)x_fm_f)[row0 * 8 + i];
        }
        __syncthreads();
        float accv[TR];
#pragma unroll
        for (int r = 0; r < TR; r++) accv[r] = 0.0f;
        for (int p = 0; p < 96; p += 4) {
            unsigned w0 = wf[(p + 0) * HID + c], w1 = wf[(p + 1) * HID + c];
            unsigned w2 = wf[(p + 2) * HID + c], w3 = wf[(p + 3) * HID + c];
#pragma unroll
            for (int r = 0; r < TR; r++) {
                uint4 v = *(const uint4*)&s_in[r][p];
                accv[r] = dot2(dot2(dot2(dot2(accv[r], v.x, w0), v.y, w1), v.z, w2), v.w, w3);
            }
        }
#pragma unroll
        for (int r = 0; r < TR; r++) accv[r] = (accv[r] + bias) * (1.0f / 3.0f);
        ln_relu_colsum(accv, gc, bc, s_w, s_q, colacc, c);
    }
    unsafeAtomicAdd(&colsum[c], colacc);
}

// ---------------------------------------------------------------- generic rows (f16 packed)
// s_in pairs: [0..PA) = scaled mean from acc, [PA..PA+PB) = xB
template <int PA, int PB>
__global__ void __launch_bounds__(128, 3)
rows_f16(int ntiles, const unsigned* __restrict__ acc, const float* __restrict__ cnt,
         const unsigned* __restrict__ xB, const unsigned* __restrict__ wf,
         const float* __restrict__ bl, const float* __restrict__ ln_g,
         const float* __restrict__ ln_b, float* __restrict__ colsum) {
    const int c = threadIdx.x;  // 0..127
    __shared__ __align__(16) unsigned s_in[TR][PA + PB];
    __shared__ unsigned s_ic2[TR];
    __shared__ float s_w[2][TR], s_q[2][TR];
    const float bias = bl[c];
    const float gc = ln_g[c], bc = ln_b[c];
    float colacc = 0.0f;
    const int A4 = PA / 4, B4 = PB / 4;
    for (int tile = blockIdx.x; tile < ntiles; tile += gridDim.x) {
        const size_t row0 = (size_t)tile * TR;
        if (c < TR) {
            float ic = 1.0f / fmaxf(cnt[row0 + c], 1.0f); s_ic2[c] = pk2(ic, ic);
        }
        __syncthreads();
        for (int i = c; i < TR * A4; i += 128) {
            int r = i / A4, q = i % A4;
            uint4 v = ((const uint4*)acc)[row0 * A4 + i];
            *(uint4*)&s_in[r][q * 4] = scale4(v, s_ic2[r]);
        }
        for (int i = c; i < TR * B4; i += 128) {
            int r = i / B4, q = i % B4;
            *(uint4*)&s_in[r][PA + q * 4] = ((const uint4*)xB)[row0 * B4 + i];
        }
        __syncthreads();
        float accv[TR];
#pragma unroll
        for (int r = 0; r < TR; r++) accv[r] = 0.0f;
        for (int p = 0; p < PA + PB; p += 4) {
            unsigned w0 = wf[(p + 0) * HID + c], w1 = wf[(p + 1) * HID + c];
            unsigned w2 = wf[(p + 2) * HID + c], w3 = wf[(p + 3) * HID + c];
#pragma unroll
            for (int r = 0; r < TR; r++) {
                uint4 v = *(const uint4*)&s_in[r][p];
                accv[r] = dot2(dot2(dot2(dot2(accv[r], v.x, w0), v.y, w1), v.z, w2), v.w, w3);
            }
        }
#pragma unroll
        for (int r = 0; r < TR; r++) accv[r] += bias;
        ln_relu_colsum(accv, gc, bc, s_w, s_q, colacc, c);
    }
    unsafeAtomicAdd(&colsum[c], colacc);
}

// ---------------------------------------------------------------- head MLP -> scalar
__global__ void head_kernel(const float* __restrict__ colsum, const float* __restrict__ gf,
                            const float* __restrict__ W1, const float* __restrict__ b1,
                            const float* __restrict__ W2, const float* __restrict__ b2,
                            float* __restrict__ out) {
    __shared__ float h[448];
    __shared__ float h1[64];
    int t = threadIdx.x;  // 512 threads
    if (t < 128) h[t] = colsum[t] * (1.0f / N_FM);
    else if (t < 256) h[t] = colsum[t] * (1.0f / N_TP);
    else if (t < 384) h[t] = colsum[t] * (1.0f / N_SM);
    else if (t < 448) h[t] = gf[t - 384];
    __syncthreads();
    if (t < 64) {
        float a = b1[t];
        for (int k = 0; k < 448; k++) a += h[k] * W1[k * 64 + t];
        h1[t] = fmaxf(a, 0.0f);
    }
    __syncthreads();
    if (t < 64) {
        float p = h1[t] * W2[t];
#pragma unroll
        for (int off = 1; off < 64; off <<= 1) p += __shfl_xor(p, off);
        if (t == 0) out[0] = p + b2[0];
    }
}

extern "C" void kernel_launch(void* const* d_in, const int* in_sizes, int n_in,
                              void* d_out, int out_size, void* d_ws, size_t ws_size,
                              hipStream_t stream) {
    const float* x_fm = (const float*)d_in[0];
    const float* x_sm = (const float*)d_in[1];
    const float* period_vol = (const float*)d_in[2];
    const float* gf = (const float*)d_in[3];
    const float* pe_table = (const float*)d_in[4];
    const int* qoq_src = (const int*)d_in[5];
    const int* qoq_dst = (const int*)d_in[6];
    const int* bp_src = (const int*)d_in[7];
    const int* bp_dst = (const int*)d_in[8];
    const int* cp_src = (const int*)d_in[9];
    const int* cp_dst = (const int*)d_in[10];
    const int* cd_src = (const int*)d_in[11];
    const int* cd_dst = (const int*)d_in[12];
    const int* rb_src = (const int*)d_in[13];
    const int* rb_dst = (const int*)d_in[14];
    const float* qoq_Wl = (const float*)d_in[15];
    const float* qoq_bl = (const float*)d_in[16];
    const float* qoq_Wr = (const float*)d_in[17];
    const float* bp_Wl = (const float*)d_in[18];
    const float* bp_bl = (const float*)d_in[19];
    const float* bp_Wr = (const float*)d_in[20];
    const float* cp_Wl = (const float*)d_in[21];
    const float* cp_bl = (const float*)d_in[22];
    const float* cp_Wr = (const float*)d_in[23];
    const float* cd_Wl = (const float*)d_in[24];
    const float* cd_bl = (const float*)d_in[25];
    const float* cd_Wr = (const float*)d_in[26];
    const float* rb_Wl = (const float*)d_in[27];
    const float* rb_bl = (const float*)d_in[28];
    const float* rb_Wr = (const float*)d_in[29];
    const float* ln_fm_g = (const float*)d_in[30];
    const float* ln_fm_b = (const float*)d_in[31];
    const float* ln_tp_g = (const float*)d_in[32];
    const float* ln_tp_b = (const float*)d_in[33];
    const float* ln_sm_g = (const float*)d_in[34];
    const float* ln_sm_b = (const float*)d_in[35];
    const float* head_W1 = (const float*)d_in[36];
    const float* head_b1 = (const float*)d_in[37];
    const float* head_W2 = (const float*)d_in[38];
    const float* head_b2 = (const float*)d_in[39];

    // workspace layout (uint words); f16-pair accumulators first (zeroed region)
    unsigned* wsu = (unsigned*)d_ws;
    size_t off = 0;
    unsigned* acc_qoq = wsu + off; off += (size_t)N_FM * 32;  // 64 feats = 32 pairs
    unsigned* acc_cp  = wsu + off; off += (size_t)N_FM * 16;
    unsigned* acc_rb  = wsu + off; off += (size_t)N_FM * 16;
    unsigned* acc_bp  = wsu + off; off += (size_t)N_TP * 32;
    unsigned* acc_cd  = wsu + off; off += (size_t)N_SM * 16;
    float* cnt_qoq = (float*)(wsu + off); off += N_FM;
    float* cnt_cp  = (float*)(wsu + off); off += N_FM;
    float* cnt_rb  = (float*)(wsu + off); off += N_FM;
    float* cnt_bp  = (float*)(wsu + off); off += N_TP;
    float* cnt_cd  = (float*)(wsu + off); off += N_SM;
    float* colsum  = (float*)(wsu + off); off += 384;
    size_t zero_words = off;
    unsigned* pe_f    = wsu + off; off += (size_t)N_TP * 16;
    unsigned* x_fm_f  = wsu + off; off += (size_t)N_FM * 32;
    unsigned* x_sm_f  = wsu + off; off += (size_t)N_SM * 16;
    float* wr_comb    = (float*)(wsu + off); off += 64 * HID;
    unsigned* wf_fm   = wsu + off; off += 96 * HID;
    unsigned* wf_tp   = wsu + off; off += 48 * HID;
    unsigned* wf_sm   = wsu + off; off += 32 * HID;

    hipMemsetAsync(d_ws, 0, zero_words * 4, stream);

    pe_pack_kernel<<<(N_TP * 16 + 255) / 256, 256, 0, stream>>>(pe_table, period_vol, pe_f);
    pack_x_kernel<<<(N_FM * 32 + 255) / 256, 256, 0, stream>>>(x_fm, x_fm_f, N_FM * 32);
    pack_x_kernel<<<(N_SM * 16 + 255) / 256, 256, 0, stream>>>(x_sm, x_sm_f, N_SM * 16);
    wr_comb_kernel<<<(64 * HID + 255) / 256, 256, 0, stream>>>(qoq_Wr, cp_Wr, rb_Wr, wr_comb);

    // weight packs (f16 pair-rows): order matches s_in layouts
    const int PW = 256;
    pack_w_kernel<<<(32 * HID + PW - 1) / PW, PW, 0, stream>>>(qoq_Wl, wf_fm, 64);
    pack_w_kernel<<<(16 * HID + PW - 1) / PW, PW, 0, stream>>>(cp_Wl, wf_fm + 32 * HID, 32);
    pack_w_kernel<<<(16 * HID + PW - 1) / PW, PW, 0, stream>>>(rb_Wl, wf_fm + 48 * HID, 32);
    pack_w_kernel<<<(32 * HID + PW - 1) / PW, PW, 0, stream>>>(wr_comb, wf_fm + 64 * HID, 64);
    pack_w_kernel<<<(32 * HID + PW - 1) / PW, PW, 0, stream>>>(bp_Wl, wf_tp, 64);
    pack_w_kernel<<<(16 * HID + PW - 1) / PW, PW, 0, stream>>>(bp_Wr, wf_tp + 32 * HID, 32);
    pack_w_kernel<<<(16 * HID + PW - 1) / PW, PW, 0, stream>>>(cd_Wl, wf_sm, 32);
    pack_w_kernel<<<(16 * HID + PW - 1) / PW, PW, 0, stream>>>(cd_Wr, wf_sm + 16 * HID, 32);

    // edge scatters: UNR=4 edges/thread, packed-f16 atomics
    {
        int blocks;
        blocks = (int)((((E_QOQ + 3) / 4) * 32ull + 255) / 256);
        edge_scatter_f16<5, 4><<<blocks, 256, 0, stream>>>(qoq_src, qoq_dst, E_QOQ, x_fm_f, acc_qoq, cnt_qoq);
        blocks = (int)((((E_BP + 3) / 4) * 32ull + 255) / 256);
        edge_scatter_f16<5, 4><<<blocks, 256, 0, stream>>>(bp_src, bp_dst, E_BP, x_fm_f, acc_bp, cnt_bp);
        blocks = (int)((((E_CP + 3) / 4) * 16ull + 255) / 256);
        edge_scatter_f16<4, 4><<<blocks, 256, 0, stream>>>(cp_src, cp_dst, E_CP, pe_f, acc_cp, cnt_cp);
        blocks = (int)((((E_CD + 3) / 4) * 16ull + 255) / 256);
        edge_scatter_f16<4, 4><<<blocks, 256, 0, stream>>>(cd_src, cd_dst, E_CD, pe_f, acc_cd, cnt_cd);
        blocks = (int)((((E_RB + 3) / 4) * 16ull + 255) / 256);
        edge_scatter_f16<4, 4><<<blocks, 256, 0, stream>>>(rb_src, rb_dst, E_RB, pe_f, acc_rb, cnt_rb);
    }

    fm_rows_f16<<<2048, 128, 0, stream>>>(acc_qoq, cnt_qoq, acc_cp, cnt_cp, acc_rb, cnt_rb,
                                          x_fm_f, wf_fm, qoq_bl, cp_bl, rb_bl,
                                          ln_fm_g, ln_fm_b, colsum);
    rows_f16<32, 16><<<N_TP / TR, 128, 0, stream>>>(N_TP / TR, acc_bp, cnt_bp, pe_f, wf_tp,
                                                    bp_bl, ln_tp_g, ln_tp_b, colsum + 128);
    rows_f16<16, 16><<<2048, 128, 0, stream>>>(N_SM / TR, acc_cd, cnt_cd, x_sm_f, wf_sm,
                                               cd_bl, ln_sm_g, ln_sm_b, colsum + 256);

    head_kernel<<<1, 512, 0, stream>>>(colsum, gf, head_W1, head_b1, head_W2, head_b2,
                                       (float*)d_out);
}